// Round 1
// baseline (199.677 us; speedup 1.0000x reference)
//
#include <hip/hip_runtime.h>
#include <stdint.h>

#define NN 65536
#define NE 262144

typedef __attribute__((ext_vector_type(8))) short bf16x8;
typedef __attribute__((ext_vector_type(4))) float f32x4;

__device__ __forceinline__ short f2bf(float f) {
  union { float f; uint32_t u; } v; v.f = f;
  uint32_t u = v.u + 0x7fffu + ((v.u >> 16) & 1u);
  return (short)(u >> 16);
}
__device__ __forceinline__ float bf2f(short s) {
  union { uint32_t u; float f; } v; v.u = ((uint32_t)(uint16_t)s) << 16;
  return v.f;
}

// Pre-transpose + bf16-convert weights:
// w1t[n][k] (n<256, k<32, zero-padded k>=10) = w1[k][n]
// w2t[n][k] (k<256)                          = w2[k][n]
__global__ __launch_bounds__(256) void prep_weights(
    const float* __restrict__ w1_0, const float* __restrict__ w1_1,
    const float* __restrict__ w2_0, const float* __restrict__ w2_1,
    short* __restrict__ w1t0, short* __restrict__ w1t1,
    short* __restrict__ w2t0, short* __restrict__ w2t1) {
  int t = blockIdx.x * 256 + threadIdx.x;  // grid covers 65536
  if (t < 8192) {
    int n = t >> 5, k = t & 31;
    w1t0[t] = (k < 10) ? f2bf(w1_0[k * 256 + n]) : (short)0;
    w1t1[t] = (k < 10) ? f2bf(w1_1[k * 256 + n]) : (short)0;
  }
  if (t < 32768) {
    int n = t >> 8, k = t & 255;
    w2t1[t] = f2bf(w2_1[k * 128 + n]);
  }
  {
    int n = t >> 8, k = t & 255;
    w2t0[t] = f2bf(w2_0[k * 256 + n]);
  }
}

// Fused per-layer edge kernel: 64 edges/block, 4 waves.
// N2 = in*out of the generated weight (256 or 128), OUTC = out channels.
template <int N2, int OUTC, bool DO_CNT>
__global__ __launch_bounds__(256) void edge_kernel(
    const float* __restrict__ x, const int* __restrict__ ei,
    const float* __restrict__ ea, const short* __restrict__ w1t,
    const float* __restrict__ b1, const short* __restrict__ w2t,
    const float* __restrict__ b2, float* __restrict__ ssum,
    float* __restrict__ cnt) {
  __shared__ char smem[(64 * 32 + 64 * 256) * 2];  // 36 KB: eaL(4K) + hL(32K)
  char* const hB = smem + 64 * 32 * 2;
  short* const msgpre = (short*)smem;  // overlaid after GEMM2 (barrier-separated)

  const int tid = threadIdx.x;
  const int wave = tid >> 6;
  const int lane = tid & 63;
  const int g = lane >> 4;   // k-group for A/B frags
  const int lr = lane & 15;  // row (A) / col (B,D) within 16x16 tile
  const int e0 = blockIdx.x * 64;

  // ---- stage edge_attr tile [64][32] bf16 (zero-padded K), swizzled ----
  for (int idx = tid; idx < 64 * 32; idx += 256) {
    int r = idx >> 5, k = idx & 31;
    float v = (k < 10) ? ea[(size_t)(e0 + r) * 10 + k] : 0.0f;
    *(short*)(smem + ((idx * 2) ^ ((r & 7) << 4))) = f2bf(v);
  }
  __syncthreads();

  // ---- GEMM1: hpre[64][256] = eaTile @ w1 ; wave owns cols [wave*64, +64) ----
  f32x4 acc1[4][4];
#pragma unroll
  for (int mt = 0; mt < 4; ++mt)
#pragma unroll
    for (int nt = 0; nt < 4; ++nt) acc1[mt][nt] = (f32x4){0.f, 0.f, 0.f, 0.f};
  bf16x8 a1[4];
#pragma unroll
  for (int mt = 0; mt < 4; ++mt) {
    int row = mt * 16 + lr;
    a1[mt] = *(const bf16x8*)(smem + ((row * 64 + g * 16) ^ ((row & 7) << 4)));
  }
#pragma unroll
  for (int nt = 0; nt < 4; ++nt) {
    int col = wave * 64 + nt * 16 + lr;
    bf16x8 b = *(const bf16x8*)(w1t + col * 32 + g * 8);
#pragma unroll
    for (int mt = 0; mt < 4; ++mt)
      acc1[mt][nt] = __builtin_amdgcn_mfma_f32_16x16x32_bf16(a1[mt], b, acc1[mt][nt], 0, 0, 0);
  }
  // h = relu(hpre + b1) -> hL [64][256] bf16 swizzled
#pragma unroll
  for (int nt = 0; nt < 4; ++nt) {
    int col = wave * 64 + nt * 16 + lr;
    float bb = b1[col];
#pragma unroll
    for (int mt = 0; mt < 4; ++mt)
#pragma unroll
      for (int r = 0; r < 4; ++r) {
        int row = mt * 16 + g * 4 + r;
        float hv = fmaxf(acc1[mt][nt][r] + bb, 0.0f);
        *(short*)(hB + ((row * 512 + col * 2) ^ ((row & 7) << 4))) = f2bf(hv);
      }
  }
  __syncthreads();

  // ---- GEMM2: msgpre[64][N2] = h @ w2 ; B-frags straight from global w2t ----
  constexpr int NT2 = N2 / 64;  // col-tiles per wave
  f32x4 acc[4][NT2];
#pragma unroll
  for (int mt = 0; mt < 4; ++mt)
#pragma unroll
    for (int nt = 0; nt < NT2; ++nt) acc[mt][nt] = (f32x4){0.f, 0.f, 0.f, 0.f};
#pragma unroll
  for (int ks = 0; ks < 8; ++ks) {
    bf16x8 a2[4];
#pragma unroll
    for (int mt = 0; mt < 4; ++mt) {
      int row = mt * 16 + lr;
      a2[mt] = *(const bf16x8*)(hB + ((row * 512 + ks * 64 + g * 16) ^ ((row & 7) << 4)));
    }
#pragma unroll
    for (int nt = 0; nt < NT2; ++nt) {
      int col = wave * (NT2 * 16) + nt * 16 + lr;
      bf16x8 b = *(const bf16x8*)(w2t + col * 256 + ks * 32 + g * 8);
#pragma unroll
      for (int mt = 0; mt < 4; ++mt)
        acc[mt][nt] = __builtin_amdgcn_mfma_f32_16x16x32_bf16(a2[mt], b, acc[mt][nt], 0, 0, 0);
    }
  }
  __syncthreads();  // hL reads done -> safe to overlay msgpre
  // msgpre = acc + b2, bf16, plain [64][N2]
#pragma unroll
  for (int nt = 0; nt < NT2; ++nt) {
    int col = wave * (NT2 * 16) + nt * 16 + lr;
    float bb = b2[col];
#pragma unroll
    for (int mt = 0; mt < 4; ++mt)
#pragma unroll
      for (int r = 0; r < 4; ++r) {
        int row = mt * 16 + g * 4 + r;
        msgpre[row * N2 + col] = f2bf(acc[mt][nt][r] + bb);
      }
  }
  __syncthreads();

  // ---- bilinear msg[e,o] = sum_i x[src,i]*We[e,i,o] + atomic scatter ----
  for (int it = tid; it < 64 * OUTC; it += 256) {
    int e = it / OUTC, o = it % OUTC;
    int ge = e0 + e;
    int s = ei[ge];
    int d = ei[NE + ge];
    const float* xr = x + (size_t)s * 16;
    float m = 0.f;
#pragma unroll
    for (int i = 0; i < 16; ++i)
      m += xr[i] * bf2f(msgpre[e * N2 + i * OUTC + o]);
    atomicAdd(&ssum[(size_t)d * OUTC + o], m);
    if (DO_CNT && o == 0) atomicAdd(&cnt[d], 1.0f);
  }
}

// x_out = relu(ssum/max(cnt,1) + x_in @ root + bias), one thread per node
template <int OUTC>
__global__ __launch_bounds__(256) void node_kernel(
    const float* __restrict__ xin, const float* __restrict__ ssum,
    const float* __restrict__ cnt, const float* __restrict__ root,
    const float* __restrict__ bias, float* __restrict__ xout) {
  int n = blockIdx.x * 256 + threadIdx.x;  // grid exact: NN/256 blocks
  float inv = 1.0f / fmaxf(cnt[n], 1.0f);
  float xi[16];
#pragma unroll
  for (int i = 0; i < 4; ++i) {
    float4 v = ((const float4*)(xin + (size_t)n * 16))[i];
    xi[4 * i] = v.x; xi[4 * i + 1] = v.y; xi[4 * i + 2] = v.z; xi[4 * i + 3] = v.w;
  }
#pragma unroll
  for (int o = 0; o < OUTC; ++o) {
    float a = ssum[(size_t)n * OUTC + o] * inv + bias[o];
#pragma unroll
    for (int i = 0; i < 16; ++i) a += xi[i] * root[i * OUTC + o];
    xout[(size_t)n * OUTC + o] = fmaxf(a, 0.f);
  }
}

__global__ __launch_bounds__(256) void final_kernel(
    const float* __restrict__ x2, const int* __restrict__ ei,
    const float* __restrict__ fcw, const float* __restrict__ fcb,
    float* __restrict__ out) {
  int e = blockIdx.x * 256 + threadIdx.x;  // grid exact: NE/256
  int s = ei[e], d = ei[NE + e];
  float acc = fcb[0];
  const float* xs = x2 + (size_t)s * 8;
  const float* xd = x2 + (size_t)d * 8;
#pragma unroll
  for (int c = 0; c < 8; ++c) acc += xs[c] * fcw[c];
#pragma unroll
  for (int c = 0; c < 8; ++c) acc += xd[c] * fcw[8 + c];
  out[e] = 1.0f / (1.0f + __expf(-acc));
}

extern "C" void kernel_launch(void* const* d_in, const int* in_sizes, int n_in,
                              void* d_out, int out_size, void* d_ws, size_t ws_size,
                              hipStream_t stream) {
  const float* x      = (const float*)d_in[0];
  const int*   ei     = (const int*)d_in[1];
  const float* ea     = (const float*)d_in[2];
  const float* w1_0   = (const float*)d_in[3];
  const float* b1_0   = (const float*)d_in[4];
  const float* w2_0   = (const float*)d_in[5];
  const float* b2_0   = (const float*)d_in[6];
  const float* root_0 = (const float*)d_in[7];
  const float* bias_0 = (const float*)d_in[8];
  const float* w1_1   = (const float*)d_in[9];
  const float* b1_1   = (const float*)d_in[10];
  const float* w2_1   = (const float*)d_in[11];
  const float* b2_1   = (const float*)d_in[12];
  const float* root_1 = (const float*)d_in[13];
  const float* bias_1 = (const float*)d_in[14];
  const float* fc_w   = (const float*)d_in[15];
  const float* fc_b   = (const float*)d_in[16];
  float* out = (float*)d_out;

  char* ws = (char*)d_ws;
  float* ssum0 = (float*)(ws);                        // 4 MB
  float* x1    = (float*)(ws + (4u << 20));           // 4 MB
  float* ssum1 = (float*)(ws + (8u << 20));           // 2 MB
  float* x2    = (float*)(ws + (10u << 20));          // 2 MB
  float* cnt   = (float*)(ws + (12u << 20));          // 256 KB
  short* w1t0  = (short*)(ws + (12u << 20) + (256u << 10));
  short* w1t1  = w1t0 + 8192;
  short* w2t0  = w1t1 + 8192;
  short* w2t1  = w2t0 + 65536;

  hipMemsetAsync(ssum0, 0, (size_t)NN * 16 * 4, stream);
  hipMemsetAsync(ssum1, 0, (size_t)NN * 8 * 4, stream);
  hipMemsetAsync(cnt, 0, (size_t)NN * 4, stream);
  prep_weights<<<256, 256, 0, stream>>>(w1_0, w1_1, w2_0, w2_1, w1t0, w1t1, w2t0, w2t1);

  edge_kernel<256, 16, true><<<NE / 64, 256, 0, stream>>>(
      x, ei, ea, w1t0, b1_0, w2t0, b2_0, ssum0, cnt);
  node_kernel<16><<<NN / 256, 256, 0, stream>>>(x, ssum0, cnt, root_0, bias_0, x1);
  edge_kernel<128, 8, false><<<NE / 64, 256, 0, stream>>>(
      x1, ei, ea, w1t1, b1_1, w2t1, b2_1, ssum1, nullptr);
  node_kernel<8><<<NN / 256, 256, 0, stream>>>(x1, ssum1, cnt, root_1, bias_1, x2);
  final_kernel<<<NE / 256, 256, 0, stream>>>(x2, ei, fc_w, fc_b, out);
}